// Round 7
// baseline (5210.571 us; speedup 1.0000x reference)
//
#include <hip/hip_runtime.h>

#define B_ 4096
#define T_ 200
#define F_ 64
#define U_ 48
#define G_ 144
#define NSHARED 15

// LDS float-offset layout (shared by k_main / k_final):
//  sWxT : [144][68]  transposed Wx, padded      ->     0 .. 9792
//  sWhT : [144][52]  transposed Wh, padded      ->  9792 .. 17280
//  sBi  : [144]                                 -> 17280 .. 17424
//  sBr  : [144]   (k_final: out_W + out_b)      -> 17424 .. 17568
//  sX   : [16][68]   x rows, padded             -> 17568 .. 18656
//  sH   : [16][52]   h state / rh / reduction   -> 18656 .. 19488
//  sGX  : [144]      cat scratch                -> 19488 .. 19632
//  sGH  : [144]      cat scratch                -> 19632 .. 19776
//  sRH  : [48]       cat r*h scratch            -> 19776 .. 19824
//  sT   : [15*48]    (k_final only)             -> 19824 .. 20544
#define SMEM_MAIN_BYTES  (19824 * 4)
#define SMEM_FINAL_BYTES (20544 * 4)

__device__ __forceinline__ float sigmoid_(float x) { return 1.0f / (1.0f + expf(-x)); }

#define DOT4(acc, xv, wv)                  \
    do {                                   \
        acc = fmaf((xv).x, (wv).x, acc);   \
        acc = fmaf((xv).y, (wv).y, acc);   \
        acc = fmaf((xv).z, (wv).z, acc);   \
        acc = fmaf((xv).w, (wv).w, acc);   \
    } while (0)

// ---------------------------------------------------------------------------
// K1: per-timestep winner (highest batch index) for each shared id.
// winners[t*16 + k] = max{ b : ids[b][t] == k }, or -1 if absent.
// (scatter-with-duplicates: later assignment wins -> highest b.)
// ---------------------------------------------------------------------------
__global__ void k_winners(const float* __restrict__ X, int* __restrict__ winners)
{
    __shared__ int sw[NSHARED];
    const int t = blockIdx.x;
    const int tid = threadIdx.x;
    if (tid < NSHARED) sw[tid] = -1;
    __syncthreads();
    for (int b = tid; b < B_; b += blockDim.x) {
        int id = (int)X[((size_t)b * T_ + t) * F_ + 2];
        atomicMax(&sw[id], b);
    }
    __syncthreads();
    if (tid < NSHARED) winners[t * 16 + tid] = sw[tid];
}

// ---------------------------------------------------------------------------
// K2: blocks 0..255 = card GRU (16 batch elements each, 200 steps).
//     blocks 256..270 = category-RNN chain k (sequential table evolution
//     over t = 0..T-2; only the per-step winner's update survives).
// Cat formula (Python left-assoc): hc = tanh(xh + (r*h) @ Whh),
// unlike card GRU's hc = tanh(xh + r * (h @ Whh + br)).
// ALL __syncthreads() are block-uniform (round 2 had a divergent barrier).
// ---------------------------------------------------------------------------
__global__ void __launch_bounds__(768) k_main(
    const float* __restrict__ X,
    const float* __restrict__ cWx, const float* __restrict__ cWh,
    const float* __restrict__ cbi, const float* __restrict__ cbr,
    const float* __restrict__ gWx, const float* __restrict__ gWh,
    const float* __restrict__ gb,
    const int* __restrict__ winners,
    float* __restrict__ card_h, float* __restrict__ table)
{
    extern __shared__ float sm[];
    float* sWxT = sm;
    float* sWhT = sm + 9792;
    float* sBi  = sm + 17280;
    float* sBr  = sm + 17424;
    float* sX   = sm + 17568;
    float* sH   = sm + 18656;
    float* sGX  = sm + 19488;
    float* sGH  = sm + 19632;
    float* sRH  = sm + 19776;

    const int tid = threadIdx.x;
    const int bid = blockIdx.x;

    if (bid < 256) {
        // ---------------- card GRU ----------------
        for (int i = tid; i < F_ * G_; i += 768) { int f = i / G_, g = i - f * G_; sWxT[g * 68 + f] = cWx[i]; }
        for (int i = tid; i < U_ * G_; i += 768) { int u2 = i / G_, g = i - u2 * G_; sWhT[g * 52 + u2] = cWh[i]; }
        if (tid < G_) { sBi[tid] = cbi[tid]; sBr[tid] = cbr[tid]; }
        const int el = tid & 15;
        const int u  = tid >> 4;
        sH[el * 52 + u] = 0.0f;           // h0 = 0 (covers all 16x48)
        __syncthreads();

        const float bi0 = sBi[u], bi1 = sBi[u + 48], bi2 = sBi[u + 96];
        const float br0 = sBr[u], br1 = sBr[u + 48], br2 = sBr[u + 96];
        const float4* w0 = (const float4*)(sWxT + (size_t)u * 68);
        const float4* w1 = (const float4*)(sWxT + (size_t)(u + 48) * 68);
        const float4* w2 = (const float4*)(sWxT + (size_t)(u + 96) * 68);
        const float4* v0 = (const float4*)(sWhT + (size_t)u * 52);
        const float4* v1 = (const float4*)(sWhT + (size_t)(u + 48) * 52);
        const float4* v2 = (const float4*)(sWhT + (size_t)(u + 96) * 52);
        const float4* xq = (const float4*)(sX + (size_t)el * 68);
        const float4* hq = (const float4*)(sH + (size_t)el * 52);

        const float* Xb = X + (size_t)(bid * 16) * T_ * F_;
        const int e1 = tid >> 6, f1 = tid & 63;     // stage slot 1 (rows 0..11)
        const int e2 = 12 + (tid >> 6);             // stage slot 2 (rows 12..15), tid<256

        // prefetch x(t=0)
        float pre0 = Xb[(size_t)e1 * (T_ * F_) + f1];
        float pre1 = 0.0f;
        if (tid < 256) pre1 = Xb[(size_t)e2 * (T_ * F_) + f1];

        float hnew = 0.0f;
        #pragma unroll 1
        for (int t = 0; t < T_; ++t) {
            sX[e1 * 68 + f1] = pre0;
            if (tid < 256) sX[e2 * 68 + f1] = pre1;
            __syncthreads();
            if (t + 1 < T_) {   // prefetch next step's x under this step's compute
                pre0 = Xb[(size_t)e1 * (T_ * F_) + (t + 1) * F_ + f1];
                if (tid < 256) pre1 = Xb[(size_t)e2 * (T_ * F_) + (t + 1) * F_ + f1];
            }
            float az = bi0, ar = bi1, ah = bi2;
            #pragma unroll
            for (int q = 0; q < 16; ++q) {
                float4 xv = xq[q];
                float4 a = w0[q]; DOT4(az, xv, a);
                float4 b = w1[q]; DOT4(ar, xv, b);
                float4 c = w2[q]; DOT4(ah, xv, c);
            }
            float bz = br0, brr = br1, bh = br2;
            #pragma unroll
            for (int q = 0; q < 12; ++q) {
                float4 hv = hq[q];
                float4 a = v0[q]; DOT4(bz, hv, a);
                float4 b = v1[q]; DOT4(brr, hv, b);
                float4 c = v2[q]; DOT4(bh, hv, c);
            }
            float hprev = sH[el * 52 + u];
            float z  = sigmoid_(az + bz);
            float r  = sigmoid_(ar + brr);
            float hc = tanhf(ah + r * bh);            // card: r * (h @ Whh + br)
            hnew = z * hprev + (1.0f - z) * hc;
            __syncthreads();
            sH[el * 52 + u] = hnew;
        }
        card_h[(size_t)(bid * 16 + el) * U_ + u] = hnew;
    } else {
        // ---------------- category chain k ----------------
        const int k = bid - 256;
        for (int i = tid; i < F_ * G_; i += 768) { int f = i / G_, g = i - f * G_; sWxT[g * 68 + f] = gWx[i]; }
        for (int i = tid; i < U_ * G_; i += 768) { int u2 = i / G_, g = i - u2 * G_; sWhT[g * 52 + u2] = gWh[i]; }
        if (tid < G_) sBi[tid] = gb[tid];
        if (tid < U_) sH[tid] = 0.0f;   // table row k starts at zero
        __syncthreads();

        #pragma unroll 1
        for (int t = 0; t < T_ - 1; ++t) {      // updates through t = T-2 only
            int w = winners[t * 16 + k];        // block-uniform
            if (w >= 0) {
                if (tid < F_) sX[tid] = X[((size_t)w * T_ + t) * F_ + tid];
                __syncthreads();
                if (tid < G_) {                 // gx = b + x @ Wx   (all 144)
                    float gx = sBi[tid];
                    const float4* wq  = (const float4*)(sWxT + (size_t)tid * 68);
                    const float4* xq4 = (const float4*)sX;
                    #pragma unroll
                    for (int q = 0; q < 16; ++q) { float4 xv = xq4[q], a = wq[q]; DOT4(gx, xv, a); }
                    sGX[tid] = gx;
                }
                if (tid < 96) {                 // gh = h @ Wh[z,r]  (z,r gates only)
                    float gh = 0.0f;
                    const float4* vq  = (const float4*)(sWhT + (size_t)tid * 52);
                    const float4* hq4 = (const float4*)sH;
                    #pragma unroll
                    for (int q = 0; q < 12; ++q) { float4 hv = hq4[q], a = vq[q]; DOT4(gh, hv, a); }
                    sGH[tid] = gh;
                }
                __syncthreads();
                float z = 0.0f, hprev = 0.0f;
                if (tid < U_) {
                    z         = sigmoid_(sGX[tid] + sGH[tid]);
                    float r   = sigmoid_(sGX[48 + tid] + sGH[48 + tid]);
                    hprev     = sH[tid];
                    sRH[tid]  = r * hprev;      // stage (r*h) for second matvec
                }
                __syncthreads();
                float hn = 0.0f;
                if (tid < U_) {                 // hc = tanh(xh + (r*h) @ Whh)
                    float ghh = 0.0f;
                    const float4* vq = (const float4*)(sWhT + (size_t)(96 + tid) * 52);
                    const float4* rq = (const float4*)sRH;
                    #pragma unroll
                    for (int q = 0; q < 12; ++q) { float4 rv = rq[q], a = vq[q]; DOT4(ghh, rv, a); }
                    float hc = tanhf(sGX[96 + tid] + ghh);
                    hn = z * hprev + (1.0f - z) * hc;
                }
                __syncthreads();                // uniform: all sH/sRH readers done
                if (tid < U_) sH[tid] = hn;
                __syncthreads();                // uniform: write visible next step
            }
        }
        if (tid < U_) table[k * U_ + tid] = sH[tid];
    }
}

// ---------------------------------------------------------------------------
// K3: last cat step for all B (reads final table), then output head:
//     out[b] = sigmoid( card_h[b,:] . W[0:48] + cat_hn[b,:] . W[48:96] + out_b )
// ---------------------------------------------------------------------------
__global__ void __launch_bounds__(768) k_final(
    const float* __restrict__ X,
    const float* __restrict__ gWx, const float* __restrict__ gWh,
    const float* __restrict__ gb,
    const float* __restrict__ outW, const float* __restrict__ outb,
    const float* __restrict__ card_h, const float* __restrict__ table,
    float* __restrict__ out)
{
    extern __shared__ float sm[];
    float* sWxT = sm;
    float* sWhT = sm + 9792;
    float* sBi  = sm + 17280;
    float* sBr  = sm + 17424;   // out_W (96) + out_b at [96]
    float* sX   = sm + 17568;
    float* sH   = sm + 18656;   // rh buffer, then reduction buffer
    float* sT   = sm + 19824;   // final table, 15x48

    const int tid = threadIdx.x;
    const int bid = blockIdx.x;

    for (int i = tid; i < F_ * G_; i += 768) { int f = i / G_, g = i - f * G_; sWxT[g * 68 + f] = gWx[i]; }
    for (int i = tid; i < U_ * G_; i += 768) { int u2 = i / G_, g = i - u2 * G_; sWhT[g * 52 + u2] = gWh[i]; }
    if (tid < G_) sBi[tid] = gb[tid];
    if (tid < 96) sBr[tid] = outW[tid];
    if (tid == 96) sBr[96] = outb[0];
    if (tid < NSHARED * U_) sT[tid] = table[tid];
    {
        const int e1 = tid >> 6, f1 = tid & 63;
        sX[e1 * 68 + f1] = X[((size_t)(bid * 16 + e1) * T_ + (T_ - 1)) * F_ + f1];
        if (tid < 256) {
            const int e2 = 12 + (tid >> 6);
            sX[e2 * 68 + f1] = X[((size_t)(bid * 16 + e2) * T_ + (T_ - 1)) * F_ + f1];
        }
    }
    __syncthreads();

    const int el = tid & 15;
    const int u  = tid >> 4;
    const int id = (int)sX[el * 68 + 2];

    float az = sBi[u], ar = sBi[u + 48], ah = sBi[u + 96];
    {
        const float4* xq = (const float4*)(sX + (size_t)el * 68);
        const float4* w0 = (const float4*)(sWxT + (size_t)u * 68);
        const float4* w1 = (const float4*)(sWxT + (size_t)(u + 48) * 68);
        const float4* w2 = (const float4*)(sWxT + (size_t)(u + 96) * 68);
        #pragma unroll
        for (int q = 0; q < 16; ++q) {
            float4 xv = xq[q];
            float4 a = w0[q]; DOT4(az, xv, a);
            float4 b = w1[q]; DOT4(ar, xv, b);
            float4 c = w2[q]; DOT4(ah, xv, c);
        }
    }
    float bz = 0.0f, brr = 0.0f;
    {
        const float4* hq = (const float4*)(sT + (size_t)id * U_);
        const float4* v0 = (const float4*)(sWhT + (size_t)u * 52);
        const float4* v1 = (const float4*)(sWhT + (size_t)(u + 48) * 52);
        #pragma unroll
        for (int q = 0; q < 12; ++q) {
            float4 hv = hq[q];
            float4 a = v0[q]; DOT4(bz, hv, a);
            float4 b = v1[q]; DOT4(brr, hv, b);
        }
    }
    const float hprev = sT[id * U_ + u];
    const float z  = sigmoid_(az + bz);
    const float r  = sigmoid_(ar + brr);
    sH[el * 52 + u] = r * hprev;           // stage rh for (r*h) @ Whh
    __syncthreads();
    float bh = 0.0f;
    {
        const float4* rq = (const float4*)(sH + (size_t)el * 52);
        const float4* v2 = (const float4*)(sWhT + (size_t)(u + 96) * 52);
        #pragma unroll
        for (int q = 0; q < 12; ++q) {
            float4 rv = rq[q];
            float4 c = v2[q]; DOT4(bh, rv, c);
        }
    }
    float hc = tanhf(ah + bh);             // cat: (r*h) @ Whh
    float hn = z * hprev + (1.0f - z) * hc;

    float contrib = card_h[(size_t)(bid * 16 + el) * U_ + u] * sBr[u] + hn * sBr[48 + u];
    __syncthreads();           // sH rh-readers done; reuse for reduction
    sH[el * 52 + u] = contrib;
    __syncthreads();
    if (tid < 16) {
        float s = sBr[96];
        #pragma unroll
        for (int uu = 0; uu < U_; ++uu) s += sH[tid * 52 + uu];
        out[bid * 16 + tid] = sigmoid_(s);
    }
}

// ---------------------------------------------------------------------------
extern "C" void kernel_launch(void* const* d_in, const int* in_sizes, int n_in,
                              void* d_out, int out_size, void* d_ws, size_t ws_size,
                              hipStream_t stream)
{
    const float* X   = (const float*)d_in[0];
    const float* cWx = (const float*)d_in[1];
    const float* cWh = (const float*)d_in[2];
    const float* cbi = (const float*)d_in[3];
    const float* cbr = (const float*)d_in[4];
    const float* gWx = (const float*)d_in[5];
    const float* gWh = (const float*)d_in[6];
    const float* gb  = (const float*)d_in[7];
    const float* oW  = (const float*)d_in[8];
    const float* ob  = (const float*)d_in[9];
    float* out = (float*)d_out;

    char* ws = (char*)d_ws;
    int*   winners = (int*)ws;                         // 200*16*4 = 12800 B
    float* card_h  = (float*)(ws + 13056);             // 4096*48*4 = 786432 B
    float* table   = (float*)(ws + 13056 + 786432);    // 15*48*4

    hipLaunchKernelGGL(k_winners, dim3(T_), dim3(256), 0, stream, X, winners);
    hipLaunchKernelGGL(k_main, dim3(256 + NSHARED), dim3(768), SMEM_MAIN_BYTES, stream,
                       X, cWx, cWh, cbi, cbr, gWx, gWh, gb, winners, card_h, table);
    hipLaunchKernelGGL(k_final, dim3(256), dim3(768), SMEM_FINAL_BYTES, stream,
                       X, gWx, gWh, gb, oW, ob, card_h, table, out);
}